// Round 3
// baseline (246.499 us; speedup 1.0000x reference)
//
#include <hip/hip_runtime.h>

#define NATOMS 20000
#define NCHAN  64
#define K2 120
#define TILES 8                  // atom-tiles (16 atoms) per wave; block = 512 atoms

// ws layout (bytes):
//   [0 .. 524288)   W2bf  bf16[64][4096]   c*4096 + (x*16+y)*16 + i
//   [524288 .. )    W1bf  bf16[64][256]    c*256 + x*16 + y
//   [557056 .. )    W0bf  bf16[64][16]     c*16 + x
#define W1_OFF_B 524288
#define W0_OFF_B 557056

typedef __attribute__((ext_vector_type(8))) short bf16x8;
typedef __attribute__((ext_vector_type(4))) float f32x4;

__device__ inline short f2bf_rne(float x) {
    union { float f; unsigned u; } v; v.f = x;
    unsigned r = v.u + 0x7FFF + ((v.u >> 16) & 1);
    return (short)(r >> 16);
}
// pack two f32 -> two bf16 (round-half-up) in one word: low16 = a, high16 = b
__device__ inline unsigned pk_bf(float a, float b) {
    unsigned au = __float_as_uint(a) + 0x8000u;
    unsigned bu = __float_as_uint(b) + 0x8000u;
    return __builtin_amdgcn_perm(bu, au, 0x07060302u);
}
// butterfly add via DPP (no LDS): xor1=quad_perm(1,0,3,2), xor2=quad_perm(2,3,0,1),
// xor7=row_half_mirror(0x141), xor15=row_mirror(0x140); span{1,2,7,15}=span{1,2,4,8}
#define DPP_ADD(x, ctrl) ((x) + __uint_as_float((unsigned)__builtin_amdgcn_update_dpp( \
        0, (int)__float_as_uint(x), (ctrl), 0xF, 0xF, true)))

// ---------------------------------------------------------------------------
// Kernel 1: fold weights -> bf16 per-channel tensors.
// W2 part: 256 blocks; wave handles 4 consecutive xyi rows, lane = channel.
// U2 reads wave-uniform (broadcast), w2 reads coalesced (30 KB, L1-resident),
// each lane stores one ushort4 (4 consecutive xyi of its channel).
// ---------------------------------------------------------------------------
__global__ __launch_bounds__(256) void precompute_kernel(
    const float* __restrict__ U2, const float* __restrict__ U1,
    const float* __restrict__ U0, const float* __restrict__ w2,
    const float* __restrict__ w1, const float* __restrict__ w0,
    void* __restrict__ wsv)
{
    short* W2bf = (short*)wsv;
    short* W1bf = (short*)((char*)wsv + W1_OFF_B);
    short* W0bf = (short*)((char*)wsv + W0_OFF_B);
    const int b = blockIdx.x, tid = threadIdx.x;

    if (b < 256) {
        const int wv = tid >> 6, c = tid & 63;
        const int r0 = b * 16 + wv * 4;           // 4 consecutive xyi rows
        const float* u = U2 + (size_t)r0 * K2;
        float a0 = 0.f, a1 = 0.f, a2 = 0.f, a3 = 0.f;
        #pragma unroll 6
        for (int k = 0; k < K2; ++k) {
            float wk = w2[k * NCHAN + c];         // coalesced, L1-hit
            a0 += u[k]       * wk;                // wave-uniform broadcasts
            a1 += u[120 + k] * wk;
            a2 += u[240 + k] * wk;
            a3 += u[360 + k] * wk;
        }
        ushort4 o;
        o.x = (unsigned short)f2bf_rne(a0); o.y = (unsigned short)f2bf_rne(a1);
        o.z = (unsigned short)f2bf_rne(a2); o.w = (unsigned short)f2bf_rne(a3);
        *(ushort4*)&W2bf[c * 4096 + r0] = o;
    } else if (b < 320) {
        const int c = b - 256, xy = tid;
        const float* u = U1 + xy * 8;
        float a = 0.f;
        #pragma unroll
        for (int k = 0; k < 8; ++k) a += u[k] * w1[k * NCHAN + c];
        W1bf[c * 256 + xy] = f2bf_rne(a);
    } else {
        const int id = (b - 320) * 256 + tid;
        const int c = id >> 4, x = id & 15;
        const float* u = U0 + x * 4;
        float a = 0.f;
        #pragma unroll
        for (int k = 0; k < 4; ++k) a += u[k] * w0[k * NCHAN + c];
        W0bf[c * 16 + x] = f2bf_rne(a);
    }
}

// ---------------------------------------------------------------------------
// Kernel 2: out[n,c] = sum_x f_x * D[n,x],
//   D = MFMA( P , W2ext ), P[n, k=(y,i)] = f_y*f_i  (K = 256 + 16 W1 + 1 W0 -> 288)
// Block = 1 channel x 512 atoms (4 waves x 8 tiles x 16 atoms).
// B-fragments (9) register-resident per block; acc = one f32x4 per tile.
// Epilogue: 1 mul + DPP butterfly over the 16 x-lanes (no LDS shuffles).
// ---------------------------------------------------------------------------
__global__ __launch_bounds__(256) void contract_kernel(
    const float* __restrict__ nf,   // [N, 64, 16]
    const void* __restrict__ wsv,
    float* __restrict__ out)        // [N, 64]
{
    const short* W2g = (const short*)wsv;
    const short* W1g = (const short*)((const char*)wsv + W1_OFF_B);
    const short* W0g = (const short*)((const char*)wsv + W0_OFF_B);

    __shared__ __align__(16) short W2s[16 * 264];  // x-stride 264 breaks bank aliasing
    __shared__ __align__(16) short W1s[256];
    __shared__ __align__(16) short W0s[16];
    __shared__ float Fs[4][16][20];                // per-wave f tile [atom][i]

    const int c = blockIdx.y, tid = threadIdx.x;
    const int wave = tid >> 6, lane = tid & 63;
    const int m = lane & 15, q = lane >> 4;

    // --- stage channel tensors (coalesced reads; padded LDS layout) ---
    {
        const uint4* src = (const uint4*)(W2g + (size_t)c * 4096);
        #pragma unroll
        for (int s = 0; s < 2; ++s) {
            int idx = s * 256 + tid;
            uint4 v = src[idx];
            *(uint4*)&W2s[(idx >> 5) * 264 + (idx & 31) * 8] = v;
        }
        if (tid < 32) ((uint4*)W1s)[tid] = ((const uint4*)(W1g + c * 256))[tid];
        if (tid < 2)  ((uint4*)W0s)[tid] = ((const uint4*)(W0g + c * 16))[tid];
    }
    __syncthreads();

    // --- B fragments, resident for the whole block ---
    // chunk ch<8: B[k=q*8+j][x=m] = W2[c][x=m][k_global = ch*32+q*8+j]
    bf16x8 bfr[8];
    #pragma unroll
    for (int ch = 0; ch < 8; ++ch)
        bfr[ch] = *(const bf16x8*)&W2s[m * 264 + ch * 32 + q * 8];
    // chunk 8: k' = q*8+j: k'<16 -> W1[x][y=k'], k'==16 -> W0[x], else 0
    bf16x8 b8 = (bf16x8)0;
    if (q < 2) b8 = *(const bf16x8*)&W1s[m * 16 + q * 8];
    if (q == 2) b8[0] = W0s[m];

    const int aBase = blockIdx.x * (TILES * 64);

    #pragma unroll 1
    for (int t = 0; t < TILES; ++t) {
        const int a0 = aBase + (wave * TILES + t) * 16;
        const int n_at = a0 + m;                  // this lane's atom (all q groups)

        float f[16];
        if (n_at < NATOMS) {
            const float4* fp = (const float4*)(nf + ((size_t)n_at * NCHAN + c) * 16);
            #pragma unroll
            for (int j = 0; j < 4; ++j) {
                float4 v = fp[j];
                f[4*j] = v.x; f[4*j+1] = v.y; f[4*j+2] = v.z; f[4*j+3] = v.w;
            }
        } else {
            #pragma unroll
            for (int j = 0; j < 16; ++j) f[j] = 0.f;
        }
        // stage f for the epilogue cross-lane read (q==0 lanes only)
        if (q == 0) {
            #pragma unroll
            for (int j = 0; j < 4; ++j)
                *(float4*)&Fs[wave][m][j*4] = (float4){f[4*j], f[4*j+1], f[4*j+2], f[4*j+3]};
        }

        // fi8[j] = f[(q&1)*8 + j]  (i-index prepick, shared by all chunks)
        float fi8[8];
        #pragma unroll
        for (int j = 0; j < 8; ++j) fi8[j] = (q & 1) ? f[8 + j] : f[j];

        // chunk-8 A frag: q<2 -> f[q*8+j]; q==2,j==0 -> 1.0; else 0
        uint4 a8w;
        a8w.x = pk_bf(fi8[0], fi8[1]); a8w.y = pk_bf(fi8[2], fi8[3]);
        a8w.z = pk_bf(fi8[4], fi8[5]); a8w.w = pk_bf(fi8[6], fi8[7]);
        if (q >= 2) { a8w.x = (q == 2) ? 0x3F80u : 0u; a8w.y = 0; a8w.z = 0; a8w.w = 0; }

        f32x4 accA = {0.f, 0.f, 0.f, 0.f}, accB = {0.f, 0.f, 0.f, 0.f};
        accA = __builtin_amdgcn_mfma_f32_16x16x32_bf16(
                   __builtin_bit_cast(bf16x8, a8w), b8, accA, 0, 0, 0);
        #pragma unroll
        for (int ch = 0; ch < 8; ++ch) {
            // P[k] = f_y * f_i ; y = ch*2 + (q>>1), i = (q&1)*8 + j
            float fy = (q & 2) ? f[2*ch + 1] : f[2*ch];
            uint4 aw;
            aw.x = pk_bf(fy * fi8[0], fy * fi8[1]);
            aw.y = pk_bf(fy * fi8[2], fy * fi8[3]);
            aw.z = pk_bf(fy * fi8[4], fy * fi8[5]);
            aw.w = pk_bf(fy * fi8[6], fy * fi8[7]);
            bf16x8 af = __builtin_bit_cast(bf16x8, aw);
            if (ch & 1) accB = __builtin_amdgcn_mfma_f32_16x16x32_bf16(af, bfr[ch], accB, 0, 0, 0);
            else        accA = __builtin_amdgcn_mfma_f32_16x16x32_bf16(af, bfr[ch], accA, 0, 0, 0);
        }
        f32x4 acc = accA + accB;

        // --- epilogue: out[n] = sum_x f[n,x] * D[n,x];  D row = q*4+r, col = m ---
        float tr[4];
        #pragma unroll
        for (int r = 0; r < 4; ++r) {
            float fcol = Fs[wave][q*4 + r][m];
            float v = fcol * acc[r];
            v = DPP_ADD(v, 0xB1);    // quad_perm(1,0,3,2)  ~ xor1
            v = DPP_ADD(v, 0x4E);    // quad_perm(2,3,0,1)  ~ xor2
            v = DPP_ADD(v, 0x141);   // row_half_mirror     ~ xor7
            v = DPP_ADD(v, 0x140);   // row_mirror          ~ xor15
            tr[r] = v;
        }
        if (m == 0) {
            #pragma unroll
            for (int r = 0; r < 4; ++r) {
                int n = a0 + q*4 + r;
                if (n < NATOMS) out[(size_t)n * NCHAN + c] = tr[r];
            }
        }
    }
}

extern "C" void kernel_launch(void* const* d_in, const int* in_sizes, int n_in,
                              void* d_out, int out_size, void* d_ws, size_t ws_size,
                              hipStream_t stream)
{
    const float* nf = (const float*)d_in[0];
    const float* U2 = (const float*)d_in[1];
    const float* U1 = (const float*)d_in[2];
    const float* U0 = (const float*)d_in[3];
    const float* w2 = (const float*)d_in[4];
    const float* w1 = (const float*)d_in[5];
    const float* w0 = (const float*)d_in[6];
    float* out = (float*)d_out;

    precompute_kernel<<<324, 256, 0, stream>>>(U2, U1, U0, w2, w1, w0, d_ws);

    dim3 grid((NATOMS + TILES*64*4/4 - 1) / (TILES * 64), NCHAN);   // (40, 64)
    contract_kernel<<<grid, 256, 0, stream>>>(nf, d_ws, out);
}